// Round 12
// baseline (154.971 us; speedup 1.0000x reference)
//
#include <hip/hip_runtime.h>
#include <hip/hip_bf16.h>

// ---------------------------------------------------------------------------
// LIPAR attention, MI355X. B=4 N=4096 DIM=768 H=12 DH=64 S=16 M=256 C=48.
// Pipeline: rope table (packed cos/sin) | x->bf16 | W->bf16^T | qkv GEMM
//           (256x256 8-phase counted-vmcnt schedule, +rotary,+scale, fused
//           KVt transpose emission) | flash attention (swapped-QK, fixed-base
//           softmax, ones-MFMA row sums) | output GEMM (256x256 8-phase,
//           +bias).
// ---------------------------------------------------------------------------

typedef float f32x4 __attribute__((ext_vector_type(4)));
typedef short bf16x8 __attribute__((ext_vector_type(8)));

#define DEV static __device__ __forceinline__

DEV short f2bf(float f) {  // RNE float->bf16 via HW cvt
  union { __hip_bfloat16 h; unsigned short u; } cv;
  cv.h = __float2bfloat16(f);
  return (short)cv.u;
}

DEV f32x4 fz4() { f32x4 z = {0.f, 0.f, 0.f, 0.f}; return z; }

DEV void gload16(const void* g, void* l) {
  // async global->LDS, 16B per lane; LDS dest = wave-uniform base + lane*16
  __builtin_amdgcn_global_load_lds((const __attribute__((address_space(1))) void*)g,
                                   (__attribute__((address_space(3))) void*)l, 16, 0, 0);
}

// -------- rope table: csT[pos*32+jm] = (cos, sin), pos<4096, jm<32 ---------
__global__ void __launch_bounds__(256) k_rope(float2* __restrict__ csT) {
  int idx = blockIdx.x * 256 + threadIdx.x;          // 131072 total
  int pos = idx >> 5, jm = idx & 31;
  float invf = exp2f(-(float)jm * (13.287712379549449f / 32.0f)); // 10000^(-jm/32)
  float th = (float)pos * invf;
  csT[idx] = make_float2(cosf(th), sinf(th));
}

// ---------------- x (fp32) -> xb (bf16) ------------------------------------
__global__ void __launch_bounds__(256) k_cvtx(const float* __restrict__ x,
                                              short* __restrict__ xb) {
  int i = (blockIdx.x * 256 + threadIdx.x) * 8;
  float4 a = *(const float4*)(x + i);
  float4 b = *(const float4*)(x + i + 4);
  bf16x8 v;
  v[0] = f2bf(a.x); v[1] = f2bf(a.y); v[2] = f2bf(a.z); v[3] = f2bf(a.w);
  v[4] = f2bf(b.x); v[5] = f2bf(b.y); v[6] = f2bf(b.z); v[7] = f2bf(b.w);
  *(bf16x8*)(xb + i) = v;
}

// -------- W (768x768 fp32) -> Wt[j][k] = bf16(W[k][j]) (two dest bufs) -----
__global__ void __launch_bounds__(256) k_transw(const float* __restrict__ Wq,
                                                const float* __restrict__ Wkv,
                                                const float* __restrict__ Wo,
                                                const float* __restrict__ Wo0,
                                                short* __restrict__ WtQKV,
                                                short* __restrict__ WtO) {
  __shared__ float t[64][65];
  int z = blockIdx.z;
  const float* src = (z == 0) ? Wq : (z == 1) ? Wkv : (z == 2) ? Wo : Wo0;
  short* dst = (z < 2) ? (WtQKV + (size_t)z * (768 * 768))
                       : (WtO + (size_t)(z - 2) * (768 * 768));
  int k0 = blockIdx.x * 64, j0 = blockIdx.y * 64;
  int tc = threadIdx.x & 63, tr = threadIdx.x >> 6;
#pragma unroll
  for (int i = 0; i < 16; i++) {
    int r = i * 4 + tr;
    t[tc][r] = src[(size_t)(k0 + r) * 768 + j0 + tc];   // coalesced read
  }
  __syncthreads();
#pragma unroll
  for (int i = 0; i < 16; i++) {
    int r = i * 4 + tr;
    dst[(size_t)(j0 + r) * 768 + k0 + tc] = f2bf(t[r][tc]); // coalesced write
  }
}

// ======== 256x256 8-phase GEMM machinery (BK=64, 512 thr, 8 waves) =========
// LDS 128KB: AL0|AL1|BL0|BL1 (32KB each, 256 rows x 64 k bf16, 128B rows).
// Stage unit = half-tile (128 rows, 16KB) = 2 gload16/thread; source column
// chunk XOR (row&7) [r9-verified conflict-free], read-side XOR (l15&7)<<4.
// Schedule per iteration t (tiles E=2t in buf0, O=2t+1 in buf1):
//  P1:stage A(O)h0  P2:A(O)h1  P3:B(E+2)h0  P4:B(E+2)h1+vmcnt(4)
//  P5:stage A(E+2)h0 P6:A(E+2)h1 P7:B(O+2)h0 P8:B(O+2)h1+vmcnt(4)
// Safety: each stage's target region's last reader finished >=1 barrier
// earlier; vmcnt(4)+barrier => every wave's share of half-tiles landed.
#define GSTAGE_HT(dst, src, T, h, rowoff)                                      \
  {                                                                            \
    int cci_ = (((tid & 7) ^ ((tid >> 3) & 7)) << 4);                          \
    _Pragma("unroll") for (int i_ = 0; i_ < 2; i_++) {                         \
      gload16((src) + (size_t)((rowoff) + (h) * 128 + i_ * 64 + (tid >> 3)) * 1536 + \
                  (size_t)(T) * 128 + cci_,                                    \
              (dst) + (h) * 16384 + i_ * 8192 + wid * 1024);                   \
    }                                                                          \
  }

#define VMC4 { asm volatile("s_waitcnt vmcnt(4)" ::: "memory"); __builtin_amdgcn_sched_barrier(0); }
#define VMC0 { asm volatile("s_waitcnt vmcnt(0)" ::: "memory"); __builtin_amdgcn_sched_barrier(0); }

#define DS_A(q, kk) (*(const bf16x8*)(Acur + (wr * 128 + (q) * 16 + l15) * 128 + \
                                      (((kk) * 64 + lg * 16) ^ swz)))
#define DS_B(n, kk) (*(const bf16x8*)(Bcur + (wc * 64 + (n) * 16 + l15) * 128 + \
                                      (((kk) * 64 + lg * 16) ^ swz)))

#define PH(qd, VMW)                                                            \
  {                                                                            \
    if ((qd) == 0) {                                                           \
      _Pragma("unroll") for (int n_ = 0; n_ < 4; n_++) {                       \
        breg[n_][0] = DS_B(n_, 0);                                             \
        breg[n_][1] = DS_B(n_, 1);                                             \
      }                                                                        \
    }                                                                          \
    bf16x8 a00 = DS_A(2 * (qd), 0), a01 = DS_A(2 * (qd), 1);                   \
    bf16x8 a10 = DS_A(2 * (qd) + 1, 0), a11 = DS_A(2 * (qd) + 1, 1);           \
    VMW                                                                        \
    __builtin_amdgcn_s_barrier();                                              \
    asm volatile("s_waitcnt lgkmcnt(0)" ::: "memory");                         \
    __builtin_amdgcn_sched_barrier(0);                                         \
    __builtin_amdgcn_s_setprio(1);                                             \
    _Pragma("unroll") for (int n_ = 0; n_ < 4; n_++) {                         \
      acc[2 * (qd)][n_] = __builtin_amdgcn_mfma_f32_16x16x32_bf16(a00, breg[n_][0], acc[2 * (qd)][n_], 0, 0, 0); \
      acc[2 * (qd)][n_] = __builtin_amdgcn_mfma_f32_16x16x32_bf16(a01, breg[n_][1], acc[2 * (qd)][n_], 0, 0, 0); \
      acc[2 * (qd) + 1][n_] = __builtin_amdgcn_mfma_f32_16x16x32_bf16(a10, breg[n_][0], acc[2 * (qd) + 1][n_], 0, 0, 0); \
      acc[2 * (qd) + 1][n_] = __builtin_amdgcn_mfma_f32_16x16x32_bf16(a11, breg[n_][1], acc[2 * (qd) + 1][n_], 0, 0, 0); \
    }                                                                          \
    __builtin_amdgcn_s_setprio(0);                                             \
    __builtin_amdgcn_s_barrier();                                              \
  }

#define K256_LOOP(Abase, Bbase)                                                \
  GSTAGE_HT(AL0, Abase, 0, 0, r0)                                              \
  GSTAGE_HT(AL0, Abase, 0, 1, r0)                                              \
  GSTAGE_HT(BL0, Bbase, 0, 0, j0)                                              \
  GSTAGE_HT(BL0, Bbase, 0, 1, j0)                                              \
  GSTAGE_HT(BL1, Bbase, 1, 0, j0)                                              \
  GSTAGE_HT(BL1, Bbase, 1, 1, j0)                                              \
  VMC4                                                                         \
  __builtin_amdgcn_s_barrier();                                                \
  for (int t = 0; t < 6; t++) {                                                \
    bool lastt = (t == 5);                                                     \
    {                                                                          \
      const char* Acur = AL0; const char* Bcur = BL0;                          \
      bf16x8 breg[4][2];                                                       \
      GSTAGE_HT(AL1, Abase, 2 * t + 1, 0, r0)                                  \
      PH(0, )                                                                  \
      GSTAGE_HT(AL1, Abase, 2 * t + 1, 1, r0)                                  \
      PH(1, )                                                                  \
      if (!lastt) { GSTAGE_HT(BL0, Bbase, 2 * t + 2, 0, j0) }                  \
      PH(2, )                                                                  \
      if (!lastt) { GSTAGE_HT(BL0, Bbase, 2 * t + 2, 1, j0) }                  \
      PH(3, if (lastt) { VMC0 } else { VMC4 })                                 \
    }                                                                          \
    {                                                                          \
      const char* Acur = AL1; const char* Bcur = BL1;                          \
      bf16x8 breg[4][2];                                                       \
      if (!lastt) { GSTAGE_HT(AL0, Abase, 2 * t + 2, 0, r0) }                  \
      PH(0, )                                                                  \
      if (!lastt) { GSTAGE_HT(AL0, Abase, 2 * t + 2, 1, r0) }                  \
      PH(1, )                                                                  \
      if (!lastt) { GSTAGE_HT(BL1, Bbase, 2 * t + 3, 0, j0) }                  \
      PH(2, )                                                                  \
      if (!lastt) { GSTAGE_HT(BL1, Bbase, 2 * t + 3, 1, j0) }                  \
      PH(3, if (!lastt) { VMC4 })                                              \
    }                                                                          \
  }

// ---------------- QKV GEMM 256x256, 8-phase --------------------------------
// 384 blocks: xcd=bid&7, loc=bid>>3; mb=xcd*8+loc/6 (row tile), cbn=loc%6
// (cbn<3 -> Q cols, else KV). Output layout [c][pos][64] bf16; Q pre-scaled
// by DH^-0.5*log2e. KV blocks also emit k-slot-interleaved KVt[c][d][pos]
// via a 128KB LDS bounce (alias over the dead GEMM buffers).
__global__ void __launch_bounds__(512, 2) k_gemm_qkv(
    const short* __restrict__ xb, const short* __restrict__ Wt,
    const float2* __restrict__ csT,
    short* __restrict__ Qb, short* __restrict__ KVb,
    short* __restrict__ KVtw) {
  extern __shared__ char GL[];
  char* AL0 = GL;
  char* AL1 = GL + 32768;
  char* BL0 = GL + 65536;
  char* BL1 = GL + 98304;
  int bid = blockIdx.x;
  int xcd = bid & 7, loc = bid >> 3;      // 48 work items per XCD
  int mb = xcd * 8 + loc / 6;
  int cbn = loc % 6;
  bool isQ = cbn < 3;
  int r0 = mb * 256;
  int j0 = (isQ ? cbn : cbn - 3) * 256;
  const char* Abase = (const char*)xb;
  const char* Bbase = (const char*)(Wt + (isQ ? (size_t)0 : (size_t)(768 * 768)));
  int tid = threadIdx.x, lane = tid & 63, wid = tid >> 6;
  int wr = wid >> 2, wc = wid & 3;        // 2M x 4N waves
  int l15 = lane & 15, lg = lane >> 4;
  int swz = (l15 & 7) << 4;

  f32x4 acc[8][4];
#pragma unroll
  for (int i = 0; i < 8; i++)
#pragma unroll
    for (int j = 0; j < 4; j++) acc[i][j] = fz4();

  K256_LOOP(Abase, Bbase)

  // epilogue: rotary + store; KV blocks also LDS-bounce for KVt
  int h = (isQ ? cbn : cbn - 3) * 4 + wc;
  short* Ob = isQ ? Qb : KVb;
  float scl = isQ ? 0.18033688011112042f : 1.0f;  // DH^-0.5 * log2(e)
  bool dofuse = (!isQ) && (KVtw != nullptr);
  short* LB = (short*)GL;                  // 256 rows x 256 shorts = 128KB
#pragma unroll
  for (int m = 0; m < 8; m++) {
#pragma unroll
    for (int rg = 0; rg < 4; rg++) {
      int r = r0 + wr * 128 + m * 16 + lg * 4 + rg;
      int b = r >> 12, pos = r & 4095;
      const float2* cp = csT + pos * 32;
      float2 cs0 = cp[l15], cs1 = cp[16 + l15];
      float v0 = acc[m][0][rg], v1 = acc[m][1][rg];
      float v2 = acc[m][2][rg], v3 = acc[m][3][rg];
      short o0 = f2bf((v0 * cs0.x - v2 * cs0.y) * scl);  // d<32
      short o1 = f2bf((v1 * cs1.x - v3 * cs1.y) * scl);
      short o2 = f2bf((v2 * cs0.x + v0 * cs0.y) * scl);  // d>=32
      short o3 = f2bf((v3 * cs1.x + v1 * cs1.y) * scl);
      size_t base = ((size_t)((b * 12 + h) * 4096 + pos)) * 64 + l15;
      Ob[base] = o0; Ob[base + 16] = o1; Ob[base + 32] = o2; Ob[base + 48] = o3;
      if (dofuse) {
        int ptl = wr * 128 + m * 16 + lg * 4 + rg;   // pos within tile
        int g = ptl >> 5, w = ptl & 31;
        int pp = g * 32 + 8 * ((w & 15) >> 2) + 4 * ((w >> 4) & 1) + (w & 3);
        int ch = pp >> 3, sub = pp & 7;
        short ov[4] = {o0, o1, o2, o3};
#pragma unroll
        for (int n = 0; n < 4; n++) {
          int rowd = wc * 64 + n * 16 + l15;         // global col in tile
          LB[rowd * 256 + (((ch ^ (rowd & 31)) << 3) + sub)] = ov[n];
        }
      }
    }
  }
  if (dofuse) {
    __syncthreads();
    int b = r0 >> 12, pos0 = r0 & 4095, hb = (cbn - 3) * 4;
#pragma unroll
    for (int z = 0; z < 16; z++) {
      int rr = z * 16 + (tid >> 5);       // 0..255 (head*64 + d)
      int ck = tid & 31;                  // 16B chunk within 512B pos-row
      bf16x8 v = *(const bf16x8*)&LB[rr * 256 + ((ck ^ (rr & 31)) << 3)];
      *(bf16x8*)&KVtw[((size_t)((b * 12 + hb + (rr >> 6)) * 64 + (rr & 63))) * 4096 +
                      pos0 + ck * 8] = v;
    }
  }
}

// ------ standalone KV transpose (legacy path when ws too small) ------------
__global__ void __launch_bounds__(256) k_transkv(const short* __restrict__ KVb,
                                                 short* __restrict__ KVt) {
  __shared__ short T[64][72];
  int c = blockIdx.x;
  int pt = blockIdx.y;           // 64-pos tile
  int t = threadIdx.x;
  int ch = t & 7, rr = t >> 3;   // chunk-of-8, row (0..31)
#pragma unroll
  for (int i = 0; i < 2; i++) {
    int p = rr + i * 32;
    bf16x8 v = *(const bf16x8*)&KVb[((size_t)c * 4096 + pt * 64 + p) * 64 + ch * 8];
    *(bf16x8*)&T[p][ch * 8] = v;
  }
  __syncthreads();
#pragma unroll
  for (int i = 0; i < 2; i++) {
    int d = rr + i * 32;
    bf16x8 v;
#pragma unroll
    for (int j = 0; j < 8; j++) {
      int cc = ch * 8 + j;
      int g = cc >> 5, sig = cc & 31;
      int p = g * 32 + 4 * (sig >> 3) + (sig & 3) + 16 * ((sig >> 2) & 1);
      v[j] = T[p][d];
    }
    *(bf16x8*)&KVt[((size_t)c * 64 + d) * 4096 + pt * 64 + ch * 8] = v;
  }
}

// ---------------- flash attention (swapped-QK, fixed-base softmax) ---------
#define STAGE(buf, kk0)                                                        \
  {                                                                            \
    _Pragma("unroll") for (int i = 0; i < 2; i++) {                            \
      gload16(KVc + (size_t)((kk0) + i * 32 + krow) * 128 + ksrccol,           \
              (char*)Kl[buf] + i * 4096 + wid * 1024);                         \
      gload16(KVtc + ((size_t)(i * 32 + krow) * 4096 + (kk0)) * 2 + ksrccol,   \
              (char*)Vl[buf] + i * 4096 + wid * 1024);                         \
    }                                                                          \
  }

__global__ void __launch_bounds__(256, 4) k_attn(const short* __restrict__ Qb,
                                                 const short* __restrict__ KVbp,
                                                 const short* __restrict__ KVtp,
                                                 short* __restrict__ AO) {
  __shared__ short Kl[2][4096];    // [64 key][64 d] rows 128B, XOR-swizzled
  __shared__ short Vl[2][4096];    // [64 d][64 key(slot-interleaved)] 128B rows
  int bid = blockIdx.x;
  int orig = (bid & 7) * 192 + (bid >> 3);
  int c = orig >> 5;
  int e = orig & 31;               // 0,1 -> s=0 halves; 2..31 -> s=1..15 halves
  int s = (e < 2) ? 0 : ((e - 2) >> 1) + 1;
  int qh = (e < 2) ? e : (e - 2) & 1;
  int NC = (s == 0) ? 4 : 8;
  int Kbase = (s == 0) ? 0 : (s - 1) * 256;

  int tid = threadIdx.x, lane = tid & 63, wid = tid >> 6;
  int l15 = lane & 15, lg = lane >> 4;
  const char* KVc = (const char*)(KVbp + (size_t)c * 4096 * 64);
  const char* KVtc = (const char*)(KVtp + (size_t)c * 64 * 4096);

  int krow = tid >> 3;                 // 0..31
  int ksrccol = ((tid & 7) * 16) ^ ((krow & 7) << 4);
  int swz = (l15 & 7) << 4;            // read-side XOR

  int q0 = s * 256 + qh * 128 + wid * 32;
  bf16x8 qf[2][2];
#pragma unroll
  for (int qt = 0; qt < 2; qt++) {
    const short* Qr = Qb + ((size_t)c * 4096 + q0 + qt * 16 + l15) * 64 + lg * 8;
    qf[qt][0] = *(const bf16x8*)Qr;
    qf[qt][1] = *(const bf16x8*)(Qr + 32);
  }

  const f32x4 mi = {-32.f, -32.f, -32.f, -32.f};  // fixed softmax base
  bf16x8 ones;
#pragma unroll
  for (int j = 0; j < 8; j++) ones[j] = (short)0x3F80;  // 1.0 bf16

  f32x4 oacc[2][4];      // [qt][vt]: query=lg*4+r, d=vt*16+l15
  f32x4 lacc[2];         // [qt]: row sums (all cols identical)
#pragma unroll
  for (int qt = 0; qt < 2; qt++) {
    lacc[qt] = fz4();
#pragma unroll
    for (int vt = 0; vt < 4; vt++) oacc[qt][vt] = fz4();
  }

  STAGE(0, Kbase)
  for (int ch = 0; ch < NC; ch++) {
    int cb = ch & 1;
    __syncthreads();                       // drains vmcnt(0): buf[cb] ready
    if (ch + 1 < NC) STAGE(cb ^ 1, Kbase + (ch + 1) * 64)
    const char* Kb_ = (const char*)Kl[cb];
    const char* Vb_ = (const char*)Vl[cb];
#pragma unroll
    for (int u = 0; u < 2; u++) {          // 32-key group
      f32x4 z[2][2];
#pragma unroll
      for (int t2 = 0; t2 < 2; t2++) {     // key tile kt = 2u+t2
        const char* Kp = Kb_ + ((2 * u + t2) * 16 + l15) * 128;
        bf16x8 kf0 = *(const bf16x8*)(Kp + ((lg * 16) ^ swz));
        bf16x8 kf1 = *(const bf16x8*)(Kp + ((64 + lg * 16) ^ swz));
        __builtin_amdgcn_s_setprio(1);
#pragma unroll
        for (int qt = 0; qt < 2; qt++) {
          f32x4 zz = __builtin_amdgcn_mfma_f32_16x16x32_bf16(kf0, qf[qt][0], mi, 0, 0, 0);
          zz = __builtin_amdgcn_mfma_f32_16x16x32_bf16(kf1, qf[qt][1], zz, 0, 0, 0);
          z[qt][t2] = zz;
        }
        __builtin_amdgcn_s_setprio(0);
      }
      bf16x8 pf[2];
#pragma unroll
      for (int qt = 0; qt < 2; qt++) {
#pragma unroll
        for (int t2 = 0; t2 < 2; t2++)
#pragma unroll
          for (int r = 0; r < 4; r++)
            pf[qt][t2 * 4 + r] = f2bf(exp2f(z[qt][t2][r]));
      }
      bf16x8 vf[4];
#pragma unroll
      for (int vt = 0; vt < 4; vt++)
        vf[vt] = *(const bf16x8*)(Vb_ + (vt * 16 + l15) * 128 +
                                  ((u * 64 + lg * 16) ^ swz));
      __builtin_amdgcn_s_setprio(1);
#pragma unroll
      for (int qt = 0; qt < 2; qt++) {
#pragma unroll
        for (int vt = 0; vt < 4; vt++)
          oacc[qt][vt] = __builtin_amdgcn_mfma_f32_16x16x32_bf16(pf[qt], vf[vt], oacc[qt][vt], 0, 0, 0);
        lacc[qt] = __builtin_amdgcn_mfma_f32_16x16x32_bf16(pf[qt], ones, lacc[qt], 0, 0, 0);
      }
      __builtin_amdgcn_s_setprio(0);
    }
  }

  int bq = c / 12, hh = c % 12;
#pragma unroll
  for (int qt = 0; qt < 2; qt++) {
    float rinv[4];
#pragma unroll
    for (int r = 0; r < 4; r++) rinv[r] = 1.0f / lacc[qt][r];
#pragma unroll
    for (int vt = 0; vt < 4; vt++)
#pragma unroll
      for (int r = 0; r < 4; r++) {
        size_t row = (size_t)bq * 4096 + q0 + qt * 16 + lg * 4 + r;
        AO[row * 768 + hh * 64 + vt * 16 + l15] = f2bf(oacc[qt][vt][r] * rinv[r]);
      }
  }
}

// ---------------- output GEMM 256x256, 8-phase (+bias) ---------------------
// 192 blocks: xcd=bid&7, loc=bid>>3; mb=xcd*8+loc/3, jn=loc%3.
__global__ void __launch_bounds__(512, 2) k_gemm_out(
    const short* __restrict__ AO, const short* __restrict__ Wt,
    const float* __restrict__ bo, const float* __restrict__ bo0,
    float* __restrict__ out) {
  extern __shared__ char GL[];
  char* AL0 = GL;
  char* AL1 = GL + 32768;
  char* BL0 = GL + 65536;
  char* BL1 = GL + 98304;
  int bid = blockIdx.x;
  int xcd = bid & 7, loc = bid >> 3;      // 24 work items per XCD
  int mb = xcd * 8 + loc / 3;
  int jn = loc % 3;
  int r0 = mb * 256;
  int j0 = jn * 256;
  bool o0sel = (r0 & 4095) < 256;  // first 256 tokens of each batch -> Wo0/bo0
  const char* Abase = (const char*)AO;
  const char* Bbase = (const char*)(Wt + (o0sel ? (size_t)1 : (size_t)0) * (768 * 768));
  const float* bias = o0sel ? bo0 : bo;
  int tid = threadIdx.x, lane = tid & 63, wid = tid >> 6;
  int wr = wid >> 2, wc = wid & 3;
  int l15 = lane & 15, lg = lane >> 4;
  int swz = (l15 & 7) << 4;

  f32x4 acc[8][4];
#pragma unroll
  for (int i = 0; i < 8; i++)
#pragma unroll
    for (int j = 0; j < 4; j++) acc[i][j] = fz4();

  K256_LOOP(Abase, Bbase)

  float bs[4];
#pragma unroll
  for (int n = 0; n < 4; n++) bs[n] = bias[j0 + wc * 64 + n * 16 + l15];
#pragma unroll
  for (int m = 0; m < 8; m++)
#pragma unroll
    for (int rg = 0; rg < 4; rg++) {
      size_t r = (size_t)r0 + wr * 128 + m * 16 + lg * 4 + rg;
      float* op = out + r * 768 + j0 + wc * 64 + l15;
      op[0]  = acc[m][0][rg] + bs[0];
      op[16] = acc[m][1][rg] + bs[1];
      op[32] = acc[m][2][rg] + bs[2];
      op[48] = acc[m][3][rg] + bs[3];
    }
}

// ---------------------------------------------------------------------------
extern "C" void kernel_launch(void* const* d_in, const int* in_sizes, int n_in,
                              void* d_out, int out_size, void* d_ws, size_t ws_size,
                              hipStream_t stream) {
  (void)in_sizes; (void)n_in; (void)out_size;
  const float* x   = (const float*)d_in[0];
  const float* Wq  = (const float*)d_in[1];
  const float* Wkv = (const float*)d_in[2];
  const float* Wo  = (const float*)d_in[3];
  const float* bo  = (const float*)d_in[4];
  const float* Wo0 = (const float*)d_in[5];
  const float* bo0 = (const float*)d_in[6];
  float* out = (float*)d_out;

  char* ws = (char*)d_ws;
  // Common big buffers:
  //   xb/AO 0..25165824 | Qb ..50331648 | KVb ..75497472 | KVt ..100663296
  short* xb  = (short*)(ws + 0);
  short* AO  = xb;  // alias: xb dead after qkv GEMM
  short* Qb  = (short*)(ws + 25165824);
  short* KVb = (short*)(ws + 50331648);
  short* KVt = (short*)(ws + 75497472);

  // Fused layout (needs ws >= 106430464): csT/WtQKV/WtO after KVt.
  // Legacy layout: WtQKV+csT alias inside KVt (dead until transkv), WtO at
  // 100663296, separate k_transkv dispatch.
  bool fused = ws_size >= 106430464u;
  float2* csT;
  short *WtQKV, *WtO;
  if (fused) {
    csT   = (float2*)(ws + 100663296);    // 1,048,576
    WtQKV = (short*)(ws + 101711872);     // 2,359,296
    WtO   = (short*)(ws + 104071168);     // 2,359,296 -> end 106,430,464
  } else {
    WtQKV = (short*)(ws + 75497472);      // alias into KVt region
    csT   = (float2*)(ws + 77856768);     // alias into KVt region (1 MB)
    WtO   = (short*)(ws + 100663296);
  }

  k_rope<<<512, 256, 0, stream>>>(csT);
  k_cvtx<<<6144, 256, 0, stream>>>(x, xb);
  k_transw<<<dim3(12, 12, 4), 256, 0, stream>>>(Wq, Wkv, Wo, Wo0, WtQKV, WtO);
  k_gemm_qkv<<<384, 512, 131072, stream>>>(xb, WtQKV, csT, Qb, KVb,
                                           fused ? KVt : (short*)nullptr);
  if (!fused) k_transkv<<<dim3(48, 64), 256, 0, stream>>>(KVb, KVt);
  k_attn<<<1536, 256, 0, stream>>>(Qb, KVb, KVt, AO);
  k_gemm_out<<<192, 512, 131072, stream>>>(AO, WtO, bo, bo0, out);
}

// Round 13
// 142.378 us; speedup vs baseline: 1.0884x; 1.0884x over previous
//
#include <hip/hip_runtime.h>
#include <hip/hip_bf16.h>

// ---------------------------------------------------------------------------
// LIPAR attention, MI355X. B=4 N=4096 DIM=768 H=12 DH=64 S=16 M=256 C=48.
// Pipeline: fused prologue (rope table + x->bf16 + W->bf16^T, one dispatch) |
//           qkv GEMM (BK=64 dbuf, conflict-free swizzle, +rotary,+scale,
//           fused KVt transpose emission) | flash attention (swapped-QK,
//           fixed-base softmax, ones-MFMA row sums) | output GEMM (BK=64
//           dbuf, +bias).
// ---------------------------------------------------------------------------

typedef float f32x4 __attribute__((ext_vector_type(4)));
typedef short bf16x8 __attribute__((ext_vector_type(8)));

#define DEV static __device__ __forceinline__

DEV short f2bf(float f) {  // RNE float->bf16 via HW cvt
  union { __hip_bfloat16 h; unsigned short u; } cv;
  cv.h = __float2bfloat16(f);
  return (short)cv.u;
}

DEV f32x4 fz4() { f32x4 z = {0.f, 0.f, 0.f, 0.f}; return z; }

DEV void gload16(const void* g, void* l) {
  // async global->LDS, 16B per lane; LDS dest = wave-uniform base + lane*16
  __builtin_amdgcn_global_load_lds((const __attribute__((address_space(1))) void*)g,
                                   (__attribute__((address_space(3))) void*)l, 16, 0, 0);
}

// ---------------- fused prologue: rope | cvtx | transw ---------------------
// bid<512: csT[pos*32+jm]=(cos,sin). bid<6656: x->bf16 (8 elem/thread).
// else: W transpose tile (z = which W, 64x64 tile via LDS).
__global__ void __launch_bounds__(256) k_prep(
    const float* __restrict__ x, const float* __restrict__ Wq,
    const float* __restrict__ Wkv, const float* __restrict__ Wo,
    const float* __restrict__ Wo0, short* __restrict__ xb,
    short* __restrict__ WtQKV, short* __restrict__ WtO,
    float2* __restrict__ csT) {
  __shared__ float t[64][65];
  int bid = blockIdx.x;
  if (bid < 512) {
    int idx = bid * 256 + threadIdx.x;               // 131072 total
    int pos = idx >> 5, jm = idx & 31;
    float invf = exp2f(-(float)jm * (13.287712379549449f / 32.0f)); // 10000^(-jm/32)
    float th = (float)pos * invf;
    csT[idx] = make_float2(cosf(th), sinf(th));
  } else if (bid < 6656) {
    int i = ((bid - 512) * 256 + threadIdx.x) * 8;
    float4 a = *(const float4*)(x + i);
    float4 b = *(const float4*)(x + i + 4);
    bf16x8 v;
    v[0] = f2bf(a.x); v[1] = f2bf(a.y); v[2] = f2bf(a.z); v[3] = f2bf(a.w);
    v[4] = f2bf(b.x); v[5] = f2bf(b.y); v[6] = f2bf(b.z); v[7] = f2bf(b.w);
    *(bf16x8*)(xb + i) = v;
  } else {
    int w = bid - 6656;                 // 0..575
    int z = w / 144, rem = w % 144;
    int k0 = (rem / 12) * 64, j0 = (rem % 12) * 64;
    const float* src = (z == 0) ? Wq : (z == 1) ? Wkv : (z == 2) ? Wo : Wo0;
    short* dst = (z < 2) ? (WtQKV + (size_t)z * (768 * 768))
                         : (WtO + (size_t)(z - 2) * (768 * 768));
    int tc = threadIdx.x & 63, tr = threadIdx.x >> 6;
#pragma unroll
    for (int i = 0; i < 16; i++) {
      int r = i * 4 + tr;
      t[tc][r] = src[(size_t)(k0 + r) * 768 + j0 + tc];   // coalesced read
    }
    __syncthreads();
#pragma unroll
    for (int i = 0; i < 16; i++) {
      int r = i * 4 + tr;
      dst[(size_t)(j0 + r) * 768 + k0 + tc] = f2bf(t[r][tc]); // coalesced write
    }
  }
}

// ------- GEMM staging, BK=64: 128x64 tiles, 128B rows (r9-proven) ----------
#define QSTAGE64(Abuf, Bbuf, Abase, Bbase, kt)                                 \
  {                                                                            \
    int cci = (((tid & 7) ^ ((tid >> 3) & 7)) << 4);                           \
    _Pragma("unroll") for (int i = 0; i < 4; i++) {                            \
      int rowi = i * 32 + (tid >> 3);                                          \
      gload16((Abase) + (size_t)(r0 + rowi) * 1536 + (kt) * 128 + cci,         \
              (char*)(Abuf) + i * 4096 + wid * 1024);                          \
      gload16((Bbase) + (size_t)(j0 + rowi) * 1536 + (kt) * 128 + cci,         \
              (char*)(Bbuf) + i * 4096 + wid * 1024);                          \
    }                                                                          \
  }

// ---------------- QKV GEMM 128x128 tile, BK=64, dbuf -----------------------
// 1536 blocks 1D, XCD-grouped (A-panel blocks co-resident per XCD).
// cb 0..5 -> Q (heads 2cb+wc), cb 6..11 -> KV. Output layout [c][pos][64] bf16.
// Q additionally scaled by log2e so attention softmax can use exp2.
// If KVtw != null, KV blocks also emit the k-slot-interleaved transpose
// KVt[c][d][pos] via an LDS bounce (replaces the k_transkv dispatch).
__global__ void __launch_bounds__(256, 2) k_gemm_qkv(
    const short* __restrict__ xb, const short* __restrict__ Wt,
    const float2* __restrict__ csT,
    short* __restrict__ Qb, short* __restrict__ KVb,
    short* __restrict__ KVtw) {
  __shared__ short Lsh[4][8192];  // [0..1]=A dbuf, [2..3]=B dbuf; epilogue alias
  int bid = blockIdx.x;
  int xcd = bid & 7, loc = bid >> 3;       // 192 work items per XCD
  int r0 = (xcd * 16 + loc / 12) * 128;
  int cbk = loc % 12;
  bool isQ = cbk < 6;
  int cbl = isQ ? cbk : cbk - 6;
  const char* Ab = (const char*)xb;
  const char* Bb = (const char*)(Wt + (isQ ? (size_t)0 : (size_t)(768 * 768)));
  int j0 = cbl * 128;
  int tid = threadIdx.x, lane = tid & 63, wid = tid >> 6;
  int wr = wid >> 1, wc = wid & 1;
  int l15 = lane & 15, lg = lane >> 4;
  int swz = (l15 & 7) << 4;  // read-side XOR (row&7 == l15&7 for frag rows)

  f32x4 acc[4][4];
#pragma unroll
  for (int i = 0; i < 4; i++)
#pragma unroll
    for (int j = 0; j < 4; j++) acc[i][j] = fz4();

  QSTAGE64(Lsh[0], Lsh[2], Ab, Bb, 0)
  for (int kt = 0; kt < 12; kt++) {
    int cb = kt & 1;
    __syncthreads();                       // drains vmcnt(0): buf[cb] ready
    if (kt + 1 < 12) QSTAGE64(Lsh[cb ^ 1], Lsh[2 + (cb ^ 1)], Ab, Bb, kt + 1)
    const char* Ac = (const char*)Lsh[cb];
    const char* Bc = (const char*)Lsh[2 + cb];
#pragma unroll
    for (int kk = 0; kk < 2; kk++) {
      bf16x8 af[4], bfr[4];
#pragma unroll
      for (int mr = 0; mr < 4; mr++)
        af[mr] = *(const bf16x8*)(Ac + (wr * 64 + mr * 16 + l15) * 128 +
                                  ((kk * 64 + lg * 16) ^ swz));
#pragma unroll
      for (int nc = 0; nc < 4; nc++)
        bfr[nc] = *(const bf16x8*)(Bc + (wc * 64 + nc * 16 + l15) * 128 +
                                   ((kk * 64 + lg * 16) ^ swz));
#pragma unroll
      for (int mr = 0; mr < 4; mr++)
#pragma unroll
        for (int nc = 0; nc < 4; nc++)
          acc[mr][nc] = __builtin_amdgcn_mfma_f32_16x16x32_bf16(af[mr], bfr[nc], acc[mr][nc], 0, 0, 0);
    }
  }

  // epilogue: rotary (cols j and j^32 are acc[nc], acc[nc^2] in same lane)
  int h = 2 * cbl + wc;
  short* Ob = isQ ? Qb : KVb;
  float scl = isQ ? 0.18033688011112042f : 1.0f;  // DH^-0.5 * log2(e)
  short ovv[4][4][4];                             // [mr][rg][nc] rotated bf16
#pragma unroll
  for (int mr = 0; mr < 4; mr++) {
#pragma unroll
    for (int rg = 0; rg < 4; rg++) {
      int r = r0 + wr * 64 + mr * 16 + lg * 4 + rg;
      int b = r >> 12, pos = r & 4095;
      const float2* cp = csT + pos * 32;
      float2 cs0 = cp[l15], cs1 = cp[16 + l15];
      float v0 = acc[mr][0][rg], v1 = acc[mr][1][rg];
      float v2 = acc[mr][2][rg], v3 = acc[mr][3][rg];
      short o0 = f2bf((v0 * cs0.x - v2 * cs0.y) * scl);  // j<32
      short o1 = f2bf((v1 * cs1.x - v3 * cs1.y) * scl);
      short o2 = f2bf((v2 * cs0.x + v0 * cs0.y) * scl);  // j>=32
      short o3 = f2bf((v3 * cs1.x + v1 * cs1.y) * scl);
      size_t base = ((size_t)((b * 12 + h) * 4096 + pos)) * 64 + l15;
      Ob[base] = o0; Ob[base + 16] = o1; Ob[base + 32] = o2; Ob[base + 48] = o3;
      ovv[mr][rg][0] = o0; ovv[mr][rg][1] = o1;
      ovv[mr][rg][2] = o2; ovv[mr][rg][3] = o3;
    }
  }

  // fused KVt emission (KV blocks only): d-major LDS bounce, coalesced stores.
  // KVt[c][d][g*32+sig] = KV[c][g*32+key(sig)][d]; sig(p): w=p&31 ->
  // sig = 8*((w&15)>>2) + 4*((w>>4)&1) + (w&3)  (inverse of key(sig)).
  if (!isQ && KVtw) {
    __syncthreads();                      // all waves done with K-loop LDS
    short* Ovt = (short*)Lsh;             // 128 rows x 136 elem = 34816 B
#pragma unroll
    for (int mr = 0; mr < 4; mr++)
#pragma unroll
      for (int rg = 0; rg < 4; rg++) {
        int p = wr * 64 + mr * 16 + lg * 4 + rg;
        int w = p & 31, g = p >> 5;
        int sig = 8 * ((w & 15) >> 2) + 4 * ((w >> 4) & 1) + (w & 3);
        int pi = g * 32 + sig;
#pragma unroll
        for (int nc = 0; nc < 4; nc++) {
          int row = wc * 64 + nc * 16 + l15;   // d + 64*head-half
          Ovt[row * 136 + (pi ^ ((row & 3) << 4))] = ovv[mr][rg][nc];
        }
      }
    __syncthreads();
    int b = r0 >> 12, pos0 = r0 & 4095;
#pragma unroll
    for (int z = 0; z < 8; z++) {
      int rr = z * 16 + (tid >> 4);       // 0..127
      int chunk = tid & 15;               // 16B chunk within the 256B row span
      int off = rr * 136 + ((chunk * 8) ^ ((rr & 3) << 4));
      bf16x8 v = *(const bf16x8*)&Ovt[off];
      int wcr = rr >> 6, d = rr & 63;
      *(bf16x8*)&KVtw[((size_t)((b * 12 + 2 * cbl + wcr) * 64 + d)) * 4096 +
                      pos0 + chunk * 8] = v;
    }
  }
}

// ------ standalone KV transpose (legacy path when ws too small) ------------
__global__ void __launch_bounds__(256) k_transkv(const short* __restrict__ KVb,
                                                 short* __restrict__ KVt) {
  __shared__ short T[64][72];
  int c = blockIdx.x;
  int pt = blockIdx.y;           // 64-pos tile
  int t = threadIdx.x;
  int ch = t & 7, rr = t >> 3;   // chunk-of-8, row (0..31)
#pragma unroll
  for (int i = 0; i < 2; i++) {
    int p = rr + i * 32;
    bf16x8 v = *(const bf16x8*)&KVb[((size_t)c * 4096 + pt * 64 + p) * 64 + ch * 8];
    *(bf16x8*)&T[p][ch * 8] = v;
  }
  __syncthreads();
#pragma unroll
  for (int i = 0; i < 2; i++) {
    int d = rr + i * 32;
    bf16x8 v;
#pragma unroll
    for (int j = 0; j < 8; j++) {
      int cc = ch * 8 + j;
      int g = cc >> 5, sig = cc & 31;
      int p = g * 32 + 4 * (sig >> 3) + (sig & 3) + 16 * ((sig >> 2) & 1);
      v[j] = T[p][d];
    }
    *(bf16x8*)&KVt[((size_t)c * 64 + d) * 4096 + pt * 64 + ch * 8] = v;
  }
}

// ---------------- flash attention (swapped-QK, fixed-base softmax) ---------
// One dispatch, 1536 blocks, XCD-bijective c-major swizzle. Block = 128 q
// (4 waves x 32q). 64-key chunks staged dbuf via global_load_lds (XOR-swizzled
// source). QK^T computed as mfma(K,Q) -> P lands with query on l15, key on
// (lg,reg) = A-fragment layout for PV (no LDS bounce). Softmax: exp2 with
// constant base 32 folded into MFMA C-init; row-sums l via ones-MFMA.
#define STAGE(buf, kk0)                                                        \
  {                                                                            \
    _Pragma("unroll") for (int i = 0; i < 2; i++) {                            \
      gload16(KVc + (size_t)((kk0) + i * 32 + krow) * 128 + ksrccol,           \
              (char*)Kl[buf] + i * 4096 + wid * 1024);                         \
      gload16(KVtc + ((size_t)(i * 32 + krow) * 4096 + (kk0)) * 2 + ksrccol,   \
              (char*)Vl[buf] + i * 4096 + wid * 1024);                         \
    }                                                                          \
  }

__global__ void __launch_bounds__(256, 4) k_attn(const short* __restrict__ Qb,
                                                 const short* __restrict__ KVbp,
                                                 const short* __restrict__ KVtp,
                                                 short* __restrict__ AO) {
  __shared__ short Kl[2][4096];    // [64 key][64 d] rows 128B, XOR-swizzled
  __shared__ short Vl[2][4096];    // [64 d][64 key(slot-interleaved)] 128B rows
  int bid = blockIdx.x;
  int orig = (bid & 7) * 192 + (bid >> 3);
  int c = orig >> 5;
  int e = orig & 31;               // 0,1 -> s=0 halves; 2..31 -> s=1..15 halves
  int s = (e < 2) ? 0 : ((e - 2) >> 1) + 1;
  int qh = (e < 2) ? e : (e - 2) & 1;
  int NC = (s == 0) ? 4 : 8;
  int Kbase = (s == 0) ? 0 : (s - 1) * 256;

  int tid = threadIdx.x, lane = tid & 63, wid = tid >> 6;
  int l15 = lane & 15, lg = lane >> 4;
  const char* KVc = (const char*)(KVbp + (size_t)c * 4096 * 64);
  const char* KVtc = (const char*)(KVtp + (size_t)c * 64 * 4096);

  int krow = tid >> 3;                 // 0..31
  int ksrccol = ((tid & 7) * 16) ^ ((krow & 7) << 4);
  int swz = (l15 & 7) << 4;            // read-side XOR

  int q0 = s * 256 + qh * 128 + wid * 32;
  bf16x8 qf[2][2];
#pragma unroll
  for (int qt = 0; qt < 2; qt++) {
    const short* Qr = Qb + ((size_t)c * 4096 + q0 + qt * 16 + l15) * 64 + lg * 8;
    qf[qt][0] = *(const bf16x8*)Qr;
    qf[qt][1] = *(const bf16x8*)(Qr + 32);
  }

  const f32x4 mi = {-32.f, -32.f, -32.f, -32.f};  // fixed softmax base
  bf16x8 ones;
#pragma unroll
  for (int j = 0; j < 8; j++) ones[j] = (short)0x3F80;  // 1.0 bf16

  f32x4 oacc[2][4];      // [qt][vt]: query=lg*4+r, d=vt*16+l15
  f32x4 lacc[2];         // [qt]: row sums (all cols identical)
#pragma unroll
  for (int qt = 0; qt < 2; qt++) {
    lacc[qt] = fz4();
#pragma unroll
    for (int vt = 0; vt < 4; vt++) oacc[qt][vt] = fz4();
  }

  STAGE(0, Kbase)
  for (int ch = 0; ch < NC; ch++) {
    int cb = ch & 1;
    __syncthreads();                       // drains vmcnt(0): buf[cb] ready
    if (ch + 1 < NC) STAGE(cb ^ 1, Kbase + (ch + 1) * 64)
    const char* Kb_ = (const char*)Kl[cb];
    const char* Vb_ = (const char*)Vl[cb];
#pragma unroll
    for (int u = 0; u < 2; u++) {          // 32-key group
      f32x4 z[2][2];
#pragma unroll
      for (int t2 = 0; t2 < 2; t2++) {     // key tile kt = 2u+t2
        const char* Kp = Kb_ + ((2 * u + t2) * 16 + l15) * 128;
        bf16x8 kf0 = *(const bf16x8*)(Kp + ((lg * 16) ^ swz));
        bf16x8 kf1 = *(const bf16x8*)(Kp + ((64 + lg * 16) ^ swz));
        __builtin_amdgcn_s_setprio(1);
#pragma unroll
        for (int qt = 0; qt < 2; qt++) {
          f32x4 zz = __builtin_amdgcn_mfma_f32_16x16x32_bf16(kf0, qf[qt][0], mi, 0, 0, 0);
          zz = __builtin_amdgcn_mfma_f32_16x16x32_bf16(kf1, qf[qt][1], zz, 0, 0, 0);
          z[qt][t2] = zz;
        }
        __builtin_amdgcn_s_setprio(0);
      }
      bf16x8 pf[2];
#pragma unroll
      for (int qt = 0; qt < 2; qt++) {
#pragma unroll
        for (int t2 = 0; t2 < 2; t2++)
#pragma unroll
          for (int r = 0; r < 4; r++)
            pf[qt][t2 * 4 + r] = f2bf(exp2f(z[qt][t2][r]));
      }
      bf16x8 vf[4];
#pragma unroll
      for (int vt = 0; vt < 4; vt++)
        vf[vt] = *(const bf16x8*)(Vb_ + (vt * 16 + l15) * 128 +
                                  ((u * 64 + lg * 16) ^ swz));
      __builtin_amdgcn_s_setprio(1);
#pragma unroll
      for (int qt = 0; qt < 2; qt++) {
#pragma unroll
        for (int vt = 0; vt < 4; vt++)
          oacc[qt][vt] = __builtin_amdgcn_mfma_f32_16x16x32_bf16(pf[qt], vf[vt], oacc[qt][vt], 0, 0, 0);
        lacc[qt] = __builtin_amdgcn_mfma_f32_16x16x32_bf16(pf[qt], ones, lacc[qt], 0, 0, 0);
      }
      __builtin_amdgcn_s_setprio(0);
    }
  }

  int bq = c / 12, hh = c % 12;
#pragma unroll
  for (int qt = 0; qt < 2; qt++) {
    float rinv[4];
#pragma unroll
    for (int r = 0; r < 4; r++) rinv[r] = 1.0f / lacc[qt][r];
#pragma unroll
    for (int vt = 0; vt < 4; vt++)
#pragma unroll
      for (int r = 0; r < 4; r++) {
        size_t row = (size_t)bq * 4096 + q0 + qt * 16 + lg * 4 + r;
        AO[row * 768 + hh * 64 + vt * 16 + l15] = f2bf(oacc[qt][vt][r] * rinv[r]);
      }
  }
}

// ---------------- output GEMM (+bias), BK=64, dbuf -------------------------
__global__ void __launch_bounds__(256, 2) k_gemm_out(
    const short* __restrict__ AO, const short* __restrict__ Wt,
    const float* __restrict__ bo, const float* __restrict__ bo0,
    float* __restrict__ out) {
  __shared__ short Lsh[4][8192];
  int bid = blockIdx.x;
  int xcd = bid & 7, loc = bid >> 3;       // 96 work items per XCD
  int r0 = (xcd * 16 + loc / 6) * 128;
  int j0 = (loc % 6) * 128;
  bool o0sel = (r0 & 4095) < 256;  // first 256 tokens of each batch -> Wo0/bo0
  const char* Ab = (const char*)AO;
  const char* Bb = (const char*)(Wt + (o0sel ? (size_t)1 : (size_t)0) * (768 * 768));
  const float* bias = o0sel ? bo0 : bo;
  int tid = threadIdx.x, lane = tid & 63, wid = tid >> 6;
  int wr = wid >> 1, wc = wid & 1;
  int l15 = lane & 15, lg = lane >> 4;
  int swz = (l15 & 7) << 4;

  f32x4 acc[4][4];
#pragma unroll
  for (int i = 0; i < 4; i++)
#pragma unroll
    for (int j = 0; j < 4; j++) acc[i][j] = fz4();

  QSTAGE64(Lsh[0], Lsh[2], Ab, Bb, 0)
  for (int kt = 0; kt < 12; kt++) {
    int cb = kt & 1;
    __syncthreads();                       // drains vmcnt(0): buf[cb] ready
    if (kt + 1 < 12) QSTAGE64(Lsh[cb ^ 1], Lsh[2 + (cb ^ 1)], Ab, Bb, kt + 1)
    const char* Ac = (const char*)Lsh[cb];
    const char* Bc = (const char*)Lsh[2 + cb];
#pragma unroll
    for (int kk = 0; kk < 2; kk++) {
      bf16x8 af[4], bfr[4];
#pragma unroll
      for (int mr = 0; mr < 4; mr++)
        af[mr] = *(const bf16x8*)(Ac + (wr * 64 + mr * 16 + l15) * 128 +
                                  ((kk * 64 + lg * 16) ^ swz));
#pragma unroll
      for (int nc = 0; nc < 4; nc++)
        bfr[nc] = *(const bf16x8*)(Bc + (wc * 64 + nc * 16 + l15) * 128 +
                                   ((kk * 64 + lg * 16) ^ swz));
#pragma unroll
      for (int mr = 0; mr < 4; mr++)
#pragma unroll
        for (int nc = 0; nc < 4; nc++)
          acc[mr][nc] = __builtin_amdgcn_mfma_f32_16x16x32_bf16(af[mr], bfr[nc], acc[mr][nc], 0, 0, 0);
    }
  }

  float bs[4];
#pragma unroll
  for (int nc = 0; nc < 4; nc++) bs[nc] = bias[j0 + wc * 64 + nc * 16 + l15];
#pragma unroll
  for (int mr = 0; mr < 4; mr++)
#pragma unroll
    for (int rg = 0; rg < 4; rg++) {
      size_t r = (size_t)r0 + wr * 64 + mr * 16 + lg * 4 + rg;
      float* op = out + r * 768 + j0 + wc * 64 + l15;
      op[0]  = acc[mr][0][rg] + bs[0];
      op[16] = acc[mr][1][rg] + bs[1];
      op[32] = acc[mr][2][rg] + bs[2];
      op[48] = acc[mr][3][rg] + bs[3];
    }
}

// ---------------------------------------------------------------------------
extern "C" void kernel_launch(void* const* d_in, const int* in_sizes, int n_in,
                              void* d_out, int out_size, void* d_ws, size_t ws_size,
                              hipStream_t stream) {
  (void)in_sizes; (void)n_in; (void)out_size;
  const float* x   = (const float*)d_in[0];
  const float* Wq  = (const float*)d_in[1];
  const float* Wkv = (const float*)d_in[2];
  const float* Wo  = (const float*)d_in[3];
  const float* bo  = (const float*)d_in[4];
  const float* Wo0 = (const float*)d_in[5];
  const float* bo0 = (const float*)d_in[6];
  float* out = (float*)d_out;

  char* ws = (char*)d_ws;
  // Common big buffers:
  //   xb/AO 0..25165824 | Qb ..50331648 | KVb ..75497472 | KVt ..100663296
  short* xb  = (short*)(ws + 0);
  short* AO  = xb;  // alias: xb dead after qkv GEMM
  short* Qb  = (short*)(ws + 25165824);
  short* KVb = (short*)(ws + 50331648);
  short* KVt = (short*)(ws + 75497472);

  // Fused layout (needs ws >= 106430464): csT/WtQKV/WtO after KVt.
  // Legacy layout (ws >= 103022592): WtQKV+csT alias inside KVt (dead until
  // transkv), WtO at 100663296, and a separate k_transkv dispatch.
  bool fused = ws_size >= 106430464u;
  float2* csT;
  short *WtQKV, *WtO;
  if (fused) {
    csT   = (float2*)(ws + 100663296);    // 1,048,576
    WtQKV = (short*)(ws + 101711872);     // 2,359,296
    WtO   = (short*)(ws + 104071168);     // 2,359,296 -> end 106,430,464
  } else {
    WtQKV = (short*)(ws + 75497472);      // alias into KVt region
    csT   = (float2*)(ws + 77856768);     // alias into KVt region (1 MB)
    WtO   = (short*)(ws + 100663296);
  }

  k_prep<<<7232, 256, 0, stream>>>(x, Wq, Wkv, Wo, Wo0, xb, WtQKV, WtO, csT);
  k_gemm_qkv<<<1536, 256, 0, stream>>>(xb, WtQKV, csT, Qb, KVb,
                                       fused ? KVt : (short*)nullptr);
  if (!fused) k_transkv<<<dim3(48, 64), 256, 0, stream>>>(KVb, KVt);
  k_attn<<<1536, 256, 0, stream>>>(Qb, KVb, KVt, AO);
  k_gemm_out<<<768, 256, 0, stream>>>(AO, WtO, bo, bo0, out);
}